// Round 12
// baseline (321.467 us; speedup 1.0000x reference)
//
#include <hip/hip_runtime.h>
#include <hip/hip_fp16.h>

#define NN 50000
#define NE 800000
#define D 64
#define EPS 1e-5f
#define NT 3125   // NN/16 row-tiles for MFMA GEMMs
#define NB1 250   // partition blocks (NB1*EPB == NE)
#define EPB 3200  // edges per partition block
#define NBIN 196  // coarse bins = ceil(NN/256)
#define SBLK 192  // scan blocks (192*256 >= NBIN*NB1)

typedef unsigned short ushort_t;
typedef unsigned int uint_t;
typedef __attribute__((ext_vector_type(8))) short bf16x8;
typedef __attribute__((ext_vector_type(4))) float f32x4;

__device__ __forceinline__ float wave_sum64(float v) {
#pragma unroll
  for (int m = 1; m <= 32; m <<= 1) v += __shfl_xor(v, m, 64);
  return v;
}
__device__ __forceinline__ float group_sum16(float v) {
#pragma unroll
  for (int m = 1; m <= 8; m <<= 1) v += __shfl_xor(v, m, 64);
  return v;
}
__device__ __forceinline__ float silu_f(float v) { return v / (1.f + __expf(-v)); }
__device__ __forceinline__ float lrelu_f(float v) { return v >= 0.f ? v : 0.2f * v; }
__device__ __forceinline__ ushort_t f2b(float x) {
  unsigned u = __float_as_uint(x);
  return (ushort_t)((u + 0x7FFFu + ((u >> 16) & 1u)) >> 16);
}
__device__ __forceinline__ float b2f(ushort_t u) {
  return __uint_as_float(((unsigned)u) << 16);
}
__device__ __forceinline__ ushort_t f2h(float x) {
  return __half_as_ushort(__float2half_rn(x));
}
__device__ __forceinline__ float h2f(unsigned u) {
  return __half2float(__ushort_as_half((ushort_t)(u & 0xFFFFu)));
}
__device__ __forceinline__ float sel4(float a, float b, float c, float d, int h) {
  float ab = (h & 1) ? b : a;
  float cd = (h & 1) ? d : c;
  return (h & 2) ? cd : ab;
}
__device__ __forceinline__ bf16x8 pack8(float4 a, float4 b) {
  bf16x8 r;
  r[0] = (short)f2b(a.x); r[1] = (short)f2b(a.y);
  r[2] = (short)f2b(a.z); r[3] = (short)f2b(a.w);
  r[4] = (short)f2b(b.x); r[5] = (short)f2b(b.y);
  r[6] = (short)f2b(b.z); r[7] = (short)f2b(b.w);
  return r;
}

// ---------- graph prep: atomic-free two-level counting sort by dst ----------

// Coarse histogram: 250 blocks x 3200 edges, 196 bins (dst>>8) in LDS.
__global__ void __launch_bounds__(256) k_hist196(const int* __restrict__ ei,
                                                 int* __restrict__ histG) {
  __shared__ int h[NBIN];
  int blk = blockIdx.x;
  for (int j = threadIdx.x; j < NBIN; j += 256) h[j] = 0;
  __syncthreads();
  int e0 = blk * EPB;
  for (int e = e0 + threadIdx.x; e < e0 + EPB; e += 256)
    atomicAdd(&h[ei[NE + e] >> 8], 1);
  __syncthreads();
  for (int j = threadIdx.x; j < NBIN; j += 256) histG[j * NB1 + blk] = h[j];
}

// Hierarchical exclusive scan over the bin-major count matrix.
__global__ void __launch_bounds__(256) k_scanMA(int* __restrict__ histG,
                                                int* __restrict__ bsum) {
  __shared__ int sm[256];
  int j = threadIdx.x;
  int i = blockIdx.x * 256 + j;
  const int TOT = NBIN * NB1;
  int v = (i < TOT) ? histG[i] : 0;
  sm[j] = v;
  __syncthreads();
  for (int off = 1; off < 256; off <<= 1) {
    int t = (j >= off) ? sm[j - off] : 0;
    __syncthreads();
    sm[j] += t;
    __syncthreads();
  }
  if (i < TOT) histG[i] = sm[j] - v;  // block-local exclusive
  if (j == 255) bsum[blockIdx.x] = sm[255];
}

__global__ void __launch_bounds__(256) k_scanMB(int* __restrict__ bsum,
                                                float* __restrict__ scal) {
  __shared__ int sm[256];
  int j = threadIdx.x;
  for (int t = j; t < 1024; t += 256) scal[t] = 0.f;
  int v = (j < SBLK) ? bsum[j] : 0;
  sm[j] = v;
  __syncthreads();
  for (int off = 1; off < 256; off <<= 1) {
    int t = (j >= off) ? sm[j - off] : 0;
    __syncthreads();
    sm[j] += t;
    __syncthreads();
  }
  if (j < SBLK) bsum[j] = sm[j] - v;
}

// Partition pass: scatter packed temp records into per-(bin,block) exclusive
// regions via LDS cursors (no global atomics). Cursor = histG + bsum offset.
// temp record: x = src | f16(ew)<<16 ; y = (dst&0xFF) | f16(ea)<<16
__global__ void __launch_bounds__(256) k_part(
    const int* __restrict__ ei, const float* __restrict__ ew,
    const float* __restrict__ ea, const int* __restrict__ histG,
    const int* __restrict__ bsum, uint2* __restrict__ rectmp,
    float* __restrict__ scal) {
  __shared__ int cur[NBIN];
  int blk = blockIdx.x;
  for (int j = threadIdx.x; j < NBIN; j += 256) {
    int idx = j * NB1 + blk;
    cur[j] = histG[idx] + bsum[idx >> 8];
  }
  __syncthreads();
  int e0 = blk * EPB;
  float asum = 0.f;
  for (int e = e0 + threadIdx.x; e < e0 + EPB; e += 256) {
    int src = ei[e];
    int dst = ei[NE + e];
    float w = ew[e];
    float a = ea[e];
    asum += a;
    int slot = atomicAdd(&cur[dst >> 8], 1);
    uint2 r;
    r.x = (uint_t)(src & 0xFFFF) | ((uint_t)f2h(w) << 16);
    r.y = (uint_t)(dst & 0xFF) | ((uint_t)f2h(a) << 16);
    rectmp[slot] = r;
  }
  float s = wave_sum64(asum);
  if ((threadIdx.x & 63) == 0) {
    int slot = (blk * 4 + (threadIdx.x >> 6)) & 63;
    atomicAdd(&scal[(size_t)slot * 16], s);
  }
}

// Final counting sort within each coarse bucket (one block per bucket):
// emits final rec (x=src|f16w, y=src|f16ea) grouped by dst, rs[], AND dinv[]
// (deg accumulated via LDS float atomics during the scatter). Block 0 thread 0
// finalizes the edge_attr mean.
__global__ void __launch_bounds__(256) k_sortfin(
    const uint2* __restrict__ rectmp, const int* __restrict__ histG,
    const int* __restrict__ bsum, uint2* __restrict__ rec, int* __restrict__ rs,
    float* __restrict__ dinv, float* __restrict__ scal) {
  __shared__ int cnt[256], sc[256], cur[256];
  __shared__ float degs[256];
  int b = blockIdx.x;
  int t = threadIdx.x;
  int i0 = b * NB1;
  int lo = histG[i0] + bsum[i0 >> 8];
  int hi = NE;
  if (b < NBIN - 1) {
    int i1 = (b + 1) * NB1;
    hi = histG[i1] + bsum[i1 >> 8];
  }
  cnt[t] = 0;
  degs[t] = 1.f;  // self-loop weight
  __syncthreads();
  for (int e = lo + t; e < hi; e += 256)
    atomicAdd(&cnt[rectmp[e].y & 0xFFu], 1);
  __syncthreads();
  int v = cnt[t];
  sc[t] = v;
  __syncthreads();
  for (int off = 1; off < 256; off <<= 1) {
    int u = (t >= off) ? sc[t - off] : 0;
    __syncthreads();
    sc[t] += u;
    __syncthreads();
  }
  int ex = sc[t] - v;  // exclusive within bucket
  int node = b * 256 + t;
  if (node < NN) rs[node] = lo + ex;
  if (b == NBIN - 1 && t == 0) rs[NN] = NE;
  cur[t] = lo + ex;
  __syncthreads();
  for (int e = lo + t; e < hi; e += 256) {
    uint2 r = rectmp[e];
    int dl = (int)(r.y & 0xFFu);
    int slot = atomicAdd(&cur[dl], 1);
    uint_t src = r.x & 0xFFFFu;
    uint2 o;
    o.x = r.x;
    o.y = src | (r.y & 0xFFFF0000u);
    rec[slot] = o;
    atomicAdd(&degs[dl], h2f(r.x >> 16));
  }
  __syncthreads();
  if (node < NN) dinv[node] = rsqrtf(degs[t]);
  if (b == 0 && t == 0) {
    float s = 0.f;
    for (int j = 0; j < 64; ++j) s += scal[(size_t)j * 16];
    scal[1] = s / (float)NE;
  }
}

// Pre-normalize GCN edge weights in place: w *= dinv[src]*dinv[dst].
// Removes the per-edge random dinv[src] gather from BOTH layers' GCN agg.
__global__ void k_norm(uint2* __restrict__ rec, const int* __restrict__ rs,
                       const float* __restrict__ dinv) {
  int i = blockIdx.x * blockDim.x + threadIdx.x;
  if (i >= NN) return;
  float di = dinv[i];
  int k1 = rs[i + 1];
  for (int k = rs[i]; k < k1; ++k) {
    uint2 r = rec[k];
    int src = (int)(r.x & 0xFFFFu);
    float wn = dinv[src] * h2f(r.x >> 16) * di;
    r.x = (r.x & 0xFFFFu) | ((uint_t)f2h(wn) << 16);
    rec[k] = r;
  }
}

// ---------- MFMA dense ops (unchanged) ----------
__global__ void __launch_bounds__(256) k_dual_gemm(
    const float* __restrict__ x, const float* __restrict__ W1,
    const float* __restrict__ W2, const float* __restrict__ b2,
    ushort_t* __restrict__ out1, float* __restrict__ out2) {
  __shared__ ushort_t wf[2 * 2 * 4 * 512];
  for (int e = threadIdx.x; e < 8192; e += 256) {
    int f = e >> 9, r = e & 511;
    int lane = r >> 3, j = r & 7;
    int m = f >> 3, s = (f >> 2) & 1, t = f & 3;
    int k = s * 32 + (lane >> 4) * 8 + j;
    int n = t * 16 + (lane & 15);
    const float* Wm = m ? W2 : W1;
    wf[e] = f2b(Wm[k * D + n]);
  }
  __syncthreads();
  int tile = blockIdx.x * 4 + (threadIdx.x >> 6);
  if (tile >= NT) return;
  int l = threadIdx.x & 63;
  int q = l >> 4, cn = l & 15;
  const float* xr = x + ((size_t)tile * 16 + cn) * D + q * 8;
  float4 xa = *(const float4*)xr;
  float4 xb = *(const float4*)(xr + 4);
  float4 xc = *(const float4*)(xr + 32);
  float4 xd = *(const float4*)(xr + 36);
  bf16x8 a0 = pack8(xa, xb), a1 = pack8(xc, xd);
  f32x4 acc1[4], acc2[4];
#pragma unroll
  for (int t = 0; t < 4; ++t) {
    bf16x8 b10 = *(const bf16x8*)&wf[(0 * 8 + 0 * 4 + t) * 512 + l * 8];
    bf16x8 b11 = *(const bf16x8*)&wf[(0 * 8 + 1 * 4 + t) * 512 + l * 8];
    bf16x8 b20 = *(const bf16x8*)&wf[(1 * 8 + 0 * 4 + t) * 512 + l * 8];
    bf16x8 b21 = *(const bf16x8*)&wf[(1 * 8 + 1 * 4 + t) * 512 + l * 8];
    f32x4 z = {0.f, 0.f, 0.f, 0.f};
    acc1[t] = __builtin_amdgcn_mfma_f32_16x16x32_bf16(a0, b10, z, 0, 0, 0);
    acc1[t] = __builtin_amdgcn_mfma_f32_16x16x32_bf16(a1, b11, acc1[t], 0, 0, 0);
    acc2[t] = __builtin_amdgcn_mfma_f32_16x16x32_bf16(a0, b20, z, 0, 0, 0);
    acc2[t] = __builtin_amdgcn_mfma_f32_16x16x32_bf16(a1, b21, acc2[t], 0, 0, 0);
  }
#pragma unroll
  for (int t = 0; t < 4; ++t) {
    float bb = b2[t * 16 + cn];
#pragma unroll
    for (int r = 0; r < 4; ++r) {
      size_t row = (size_t)tile * 16 + q * 4 + r;
      out1[row * D + t * 16 + cn] = f2b(acc1[t][r]);
      out2[row * D + t * 16 + cn] = acc2[t][r] + bb;
    }
  }
}

__global__ void __launch_bounds__(256) k_gat_node(
    const float* __restrict__ x2, const float* __restrict__ Wg,
    const float* __restrict__ att_src, const float* __restrict__ att_dst,
    const float* __restrict__ We, const float* __restrict__ a_e,
    ushort_t* __restrict__ xl, float* __restrict__ a_s, float* __restrict__ a_d,
    float* __restrict__ wea) {
  __shared__ ushort_t wf[2 * 4 * 512];
  for (int e = threadIdx.x; e < 4096; e += 256) {
    int f = e >> 9, r = e & 511;
    int lane = r >> 3, j = r & 7;
    int s = (f >> 2) & 1, t = f & 3;
    int k = s * 32 + (lane >> 4) * 8 + j;
    int n = t * 16 + (lane & 15);
    wf[e] = f2b(Wg[k * D + n]);
  }
  __syncthreads();
  if (blockIdx.x == 0 && threadIdx.x < 64) {
    int c = threadIdx.x;
    float v = group_sum16(We[c] * a_e[c]);
    if ((c & 15) == 0) wea[c >> 4] = v;
  }
  int tile = blockIdx.x * 4 + (threadIdx.x >> 6);
  if (tile >= NT) return;
  int l = threadIdx.x & 63;
  int q = l >> 4, cn = l & 15;
  const float* xr = x2 + ((size_t)tile * 16 + cn) * D + q * 8;
  float4 xa = *(const float4*)xr;
  float4 xb = *(const float4*)(xr + 4);
  float4 xc = *(const float4*)(xr + 32);
  float4 xd = *(const float4*)(xr + 36);
  bf16x8 a0 = pack8(xa, xb), a1 = pack8(xc, xd);
  f32x4 acc[4];
#pragma unroll
  for (int t = 0; t < 4; ++t) {
    bf16x8 b0 = *(const bf16x8*)&wf[(0 * 4 + t) * 512 + l * 8];
    bf16x8 b1 = *(const bf16x8*)&wf[(1 * 4 + t) * 512 + l * 8];
    f32x4 z = {0.f, 0.f, 0.f, 0.f};
    acc[t] = __builtin_amdgcn_mfma_f32_16x16x32_bf16(a0, b0, z, 0, 0, 0);
    acc[t] = __builtin_amdgcn_mfma_f32_16x16x32_bf16(a1, b1, acc[t], 0, 0, 0);
  }
#pragma unroll
  for (int t = 0; t < 4; ++t) {
    float av = att_src[t * 16 + cn];
    float dv = att_dst[t * 16 + cn];
#pragma unroll
    for (int r = 0; r < 4; ++r) {
      size_t row = (size_t)tile * 16 + q * 4 + r;
      xl[row * D + t * 16 + cn] = f2b(acc[t][r]);
      float vs = group_sum16(acc[t][r] * av);
      float vd = group_sum16(acc[t][r] * dv);
      if (cn == 0) {
        a_s[row * 4 + t] = vs;
        a_d[row * 4 + t] = vd;
      }
    }
  }
}

// ---------- aggregation kernels (2 nodes per wave) ----------

__global__ void __launch_bounds__(256) k_gcn_agg(
    const ushort_t* __restrict__ h16, const float* __restrict__ res,
    const float* __restrict__ dinv, const int* __restrict__ rs,
    const uint_t* __restrict__ rec,
    const float* __restrict__ gb, const float* __restrict__ lg, const float* __restrict__ lb,
    float* __restrict__ x2, int n) {
  __shared__ int   ss[4][64];
  __shared__ float swt[4][64];
  int w = threadIdx.x >> 6;
  int wv = (blockIdx.x * blockDim.x + threadIdx.x) >> 6;
  int iA = wv * 2;
  if (iA >= n) return;
  int iB = iA + 1;
  int l = threadIdx.x & 63;
  int half = l >> 5, cp = l & 31;
  float diA = dinv[iA], diB = dinv[iB];
  float accA = diA * diA * b2f(h16[(size_t)iA * D + l]);
  float accB = diB * diB * b2f(h16[(size_t)iB * D + l]);
  int kA = rs[iA], kA1 = rs[iA + 1];
  int kB = rs[iB], kB1 = rs[iB + 1];
  while (kA < kA1 || kB < kB1) {
    int cntA = min(32, kA1 - kA);
    int cntB = min(32, kB1 - kB);
    int src = 0; float wn = 0.f;
    int myk = half ? kB : kA;
    int mycnt = half ? cntB : cntA;
    if (cp < mycnt) {
      uint_t r = rec[2 * (size_t)(myk + cp)];
      src = (int)(r & 0xFFFFu);
      wn = h2f(r >> 16);  // pre-normalized at prep
    }
    ss[w][l] = src;
    swt[w][l] = wn;
    int nm = max(cntA, cntB);
    int j = 0;
    for (; j + 4 <= nm; j += 4) {
      int4 sa = *(const int4*)&ss[w][j];
      int4 sb = *(const int4*)&ss[w][32 + j];
      float4 wa = *(const float4*)&swt[w][j];
      float4 wb = *(const float4*)&swt[w][32 + j];
      float a0 = b2f(h16[(size_t)sa.x * D + l]);
      float b0 = b2f(h16[(size_t)sb.x * D + l]);
      float a1 = b2f(h16[(size_t)sa.y * D + l]);
      float b1 = b2f(h16[(size_t)sb.y * D + l]);
      float a2 = b2f(h16[(size_t)sa.z * D + l]);
      float b2v = b2f(h16[(size_t)sb.z * D + l]);
      float a3 = b2f(h16[(size_t)sa.w * D + l]);
      float b3 = b2f(h16[(size_t)sb.w * D + l]);
      accA = fmaf(wa.x, a0, accA); accB = fmaf(wb.x, b0, accB);
      accA = fmaf(wa.y, a1, accA); accB = fmaf(wb.y, b1, accB);
      accA = fmaf(wa.z, a2, accA); accB = fmaf(wb.z, b2v, accB);
      accA = fmaf(wa.w, a3, accA); accB = fmaf(wb.w, b3, accB);
    }
    for (; j < nm; ++j) {
      int sA = ss[w][j], sB = ss[w][32 + j];
      float wA = swt[w][j], wB = swt[w][32 + j];
      float vA = b2f(h16[(size_t)sA * D + l]);
      float vB = b2f(h16[(size_t)sB * D + l]);
      accA = fmaf(wA, vA, accA);
      accB = fmaf(wB, vB, accB);
    }
    kA += cntA; kB += cntB;
  }
  float gbv = gb[l], lgv = lg[l], lbv = lb[l];
  float x1A = silu_f(accA + gbv) + res[(size_t)iA * D + l];
  float x1B = silu_f(accB + gbv) + res[(size_t)iB * D + l];
  float muA = wave_sum64(x1A) * (1.f / 64.f);
  float muB = wave_sum64(x1B) * (1.f / 64.f);
  float dA = x1A - muA, dB = x1B - muB;
  float varA = wave_sum64(dA * dA) * (1.f / 64.f);
  float varB = wave_sum64(dB * dB) * (1.f / 64.f);
  x2[(size_t)iA * D + l] = dA * rsqrtf(varA + EPS) * lgv + lbv;
  x2[(size_t)iB * D + l] = dB * rsqrtf(varB + EPS) * lgv + lbv;
}

__global__ void __launch_bounds__(256) k_gat_agg(
    const ushort_t* __restrict__ xl16, const float* __restrict__ x2,
    const float* __restrict__ a_s, const float* __restrict__ a_d,
    const int* __restrict__ rs, const uint_t* __restrict__ rec,
    const float* __restrict__ wea, const float* __restrict__ scal,
    const float* __restrict__ bg, float* __restrict__ xout, int n) {
  __shared__ int   ss[4][64];
  __shared__ float el[4][4][68];
  int w = threadIdx.x >> 6;
  int wv = (blockIdx.x * blockDim.x + threadIdx.x) >> 6;
  int iA = wv * 2;
  if (iA >= n) return;
  int iB = iA + 1;
  int l = threadIdx.x & 63;
  int half = l >> 5, cp = l & 31;
  int hh = l >> 4;
  float4 wv4 = *(const float4*)wea;
  float mean_attr = scal[1];
  float we_h = sel4(wv4.x, wv4.y, wv4.z, wv4.w, hh);
  float ad_hA = a_d[(size_t)iA * 4 + hh], as_iA = a_s[(size_t)iA * 4 + hh];
  float ad_hB = a_d[(size_t)iB * 4 + hh], as_iB = a_s[(size_t)iB * 4 + hh];
  float eSA = __expf(lrelu_f(as_iA + ad_hA + mean_attr * we_h));
  float eSB = __expf(lrelu_f(as_iB + ad_hB + mean_attr * we_h));
  float sA = eSA, sB = eSB;
  float accA = eSA * b2f(xl16[(size_t)iA * D + l]);
  float accB = eSB * b2f(xl16[(size_t)iB * D + l]);
  const float* adp = a_d + (size_t)(half ? iB : iA) * 4;
  float4 ad4 = *(const float4*)adp;
  int kA = rs[iA], kA1 = rs[iA + 1];
  int kB = rs[iB], kB1 = rs[iB + 1];
  while (kA < kA1 || kB < kB1) {
    int cntA = min(32, kA1 - kA);
    int cntB = min(32, kB1 - kB);
    int myk = half ? kB : kA;
    int mycnt = half ? cntB : cntA;
    int src = 0;
    float e0v = 0.f, e1v = 0.f, e2v = 0.f, e3v = 0.f;
    if (cp < mycnt) {
      uint_t r = rec[2 * (size_t)(myk + cp) + 1];
      src = (int)(r & 0xFFFFu);
      float ea = h2f(r >> 16);
      float4 as4 = *(const float4*)(a_s + (size_t)src * 4);
      e0v = __expf(lrelu_f(as4.x + fmaf(ea, wv4.x, ad4.x)));
      e1v = __expf(lrelu_f(as4.y + fmaf(ea, wv4.y, ad4.y)));
      e2v = __expf(lrelu_f(as4.z + fmaf(ea, wv4.z, ad4.z)));
      e3v = __expf(lrelu_f(as4.w + fmaf(ea, wv4.w, ad4.w)));
    }
    ss[w][l] = src;
    el[w][0][l] = e0v;
    el[w][1][l] = e1v;
    el[w][2][l] = e2v;
    el[w][3][l] = e3v;
    int nm = max(cntA, cntB);
    int j = 0;
    for (; j + 4 <= nm; j += 4) {
      int4 sa = *(const int4*)&ss[w][j];
      int4 sb = *(const int4*)&ss[w][32 + j];
      float4 ea4 = *(const float4*)&el[w][hh][j];
      float4 eb4 = *(const float4*)&el[w][hh][32 + j];
      float a0 = b2f(xl16[(size_t)sa.x * D + l]);
      float b0 = b2f(xl16[(size_t)sb.x * D + l]);
      float a1 = b2f(xl16[(size_t)sa.y * D + l]);
      float b1 = b2f(xl16[(size_t)sb.y * D + l]);
      float a2 = b2f(xl16[(size_t)sa.z * D + l]);
      float b2v = b2f(xl16[(size_t)sb.z * D + l]);
      float a3 = b2f(xl16[(size_t)sa.w * D + l]);
      float b3 = b2f(xl16[(size_t)sb.w * D + l]);
      accA = fmaf(ea4.x, a0, accA); accB = fmaf(eb4.x, b0, accB);
      accA = fmaf(ea4.y, a1, accA); accB = fmaf(eb4.y, b1, accB);
      accA = fmaf(ea4.z, a2, accA); accB = fmaf(eb4.z, b2v, accB);
      accA = fmaf(ea4.w, a3, accA); accB = fmaf(eb4.w, b3, accB);
      sA += (ea4.x + ea4.y) + (ea4.z + ea4.w);
      sB += (eb4.x + eb4.y) + (eb4.z + eb4.w);
    }
    for (; j < nm; ++j) {
      int srcA = ss[w][j], srcB = ss[w][32 + j];
      float eA = el[w][hh][j], eB = el[w][hh][32 + j];
      float vA = b2f(xl16[(size_t)srcA * D + l]);
      float vB = b2f(xl16[(size_t)srcB * D + l]);
      accA = fmaf(eA, vA, accA);
      accB = fmaf(eB, vB, accB);
      sA += eA; sB += eB;
    }
    kA += cntA; kB += cntB;
  }
  float bgv = bg[l];
  float oA = accA / (sA + 1e-16f) + bgv;
  float oB = accB / (sB + 1e-16f) + bgv;
  xout[(size_t)iA * D + l] = silu_f(oA) + x2[(size_t)iA * D + l];
  xout[(size_t)iB * D + l] = silu_f(oB) + x2[(size_t)iB * D + l];
}

// ---------- launch ----------

extern "C" void kernel_launch(void* const* d_in, const int* in_sizes, int n_in,
                              void* d_out, int out_size, void* d_ws, size_t ws_size,
                              hipStream_t stream) {
  (void)in_sizes; (void)n_in; (void)out_size; (void)ws_size;
  const float* x  = (const float*)d_in[0];
  const int*   ei = (const int*)d_in[1];
  const float* ew = (const float*)d_in[2];
  const float* ea = (const float*)d_in[3];
  const float* P[2][12];
  for (int l = 0; l < 2; ++l)
    for (int j = 0; j < 12; ++j) P[l][j] = (const float*)d_in[4 + l * 12 + j];

  float* W = (float*)d_ws;
  const size_t o_rs    = 0;                          // NN+16 ints
  const size_t o_dinv  = o_rs + NN + 16;             // NN
  const size_t o_wea   = o_dinv + NN;                // 16
  const size_t o_scal  = o_wea + 16;                 // 1024
  const size_t o_bsum  = o_scal + 1024;              // 256
  const size_t o_hist  = o_bsum + 256;               // 49152 ints
  const size_t o_rec   = o_hist + 49152;             // NE uint2
  const size_t o_rtmp  = o_rec + (size_t)NE * 2;     // NE uint2
  const size_t o_h16   = o_rtmp + (size_t)NE * 2;    // NN*D ushort
  const size_t o_xl16  = o_h16 + (size_t)NN * D / 2;
  const size_t o_res   = o_xl16 + (size_t)NN * D / 2;
  const size_t o_x2    = o_res + (size_t)NN * D;
  const size_t o_xmid  = o_x2 + (size_t)NN * D;
  const size_t o_as    = o_xmid + (size_t)NN * D;    // NN*4
  const size_t o_ad    = o_as + (size_t)NN * 4;      // NN*4

  int*      rs    = (int*)(W + o_rs);
  float*    dinv  = W + o_dinv;
  float*    wea   = W + o_wea;
  float*    scal  = W + o_scal;
  int*      bsum  = (int*)(W + o_bsum);
  int*      histG = (int*)(W + o_hist);
  uint2*    rec   = (uint2*)(W + o_rec);
  uint2*    rtmp  = (uint2*)(W + o_rtmp);
  ushort_t* h16   = (ushort_t*)(W + o_h16);
  ushort_t* xl16  = (ushort_t*)(W + o_xl16);
  float*    resb  = W + o_res;
  float*    x2b   = W + o_x2;
  float*    xmid  = W + o_xmid;
  float*    asb   = W + o_as;
  float*    adb   = W + o_ad;

  const int B = 256;
  const int gN  = (NN + B - 1) / B;
  const int gN2 = ((NN / 2) * 64 + B - 1) / B;  // 2 nodes per wave (agg kernels)
  const int gMF = (NT + 3) / 4;                 // 4 MFMA tiles per block

  k_hist196<<<NB1, B, 0, stream>>>(ei, histG);
  k_scanMA<<<SBLK, B, 0, stream>>>(histG, bsum);
  k_scanMB<<<1, B, 0, stream>>>(bsum, scal);
  k_part<<<NB1, B, 0, stream>>>(ei, ew, ea, histG, bsum, rtmp, scal);
  k_sortfin<<<NBIN, B, 0, stream>>>(rtmp, histG, bsum, rec, rs, dinv, scal);
  k_norm<<<gN, B, 0, stream>>>(rec, rs, dinv);

  const float* xin = x;
  for (int l = 0; l < 2; ++l) {
    float* xout = (l == 0) ? xmid : (float*)d_out;
    k_dual_gemm<<<gMF, B, 0, stream>>>(xin, P[l][0], P[l][2], P[l][3], h16, resb);
    k_gcn_agg<<<gN2, B, 0, stream>>>(h16, resb, dinv, rs, (const uint_t*)rec,
                                     P[l][1], P[l][4], P[l][5], x2b, NN);
    k_gat_node<<<gMF, B, 0, stream>>>(x2b, P[l][6], P[l][8], P[l][9],
                                      P[l][11], P[l][10], xl16, asb, adb, wea);
    k_gat_agg<<<gN2, B, 0, stream>>>(xl16, x2b, asb, adb, rs, (const uint_t*)rec,
                                     wea, scal, P[l][7], xout, NN);
    xin = xout;
  }
}

// Round 13
// 308.368 us; speedup vs baseline: 1.0425x; 1.0425x over previous
//
#include <hip/hip_runtime.h>
#include <hip/hip_fp16.h>

#define NN 50000
#define NE 800000
#define D 64
#define EPS 1e-5f
#define NT 3125   // NN/16 row-tiles for MFMA GEMMs
#define NB1 250   // partition blocks (NB1*EPB == NE)
#define EPB 3200  // edges per partition block
#define NBIN 196  // coarse bins = ceil(NN/256)
#define STOT 49152  // padded scan length (192*256 >= NBIN*NB1)
#define SBLK 192

typedef unsigned short ushort_t;
typedef unsigned int uint_t;
typedef __attribute__((ext_vector_type(8))) short bf16x8;
typedef __attribute__((ext_vector_type(4))) float f32x4;

__device__ __forceinline__ float wave_sum64(float v) {
#pragma unroll
  for (int m = 1; m <= 32; m <<= 1) v += __shfl_xor(v, m, 64);
  return v;
}
__device__ __forceinline__ float group_sum16(float v) {
#pragma unroll
  for (int m = 1; m <= 8; m <<= 1) v += __shfl_xor(v, m, 64);
  return v;
}
__device__ __forceinline__ float silu_f(float v) { return v / (1.f + __expf(-v)); }
__device__ __forceinline__ float lrelu_f(float v) { return v >= 0.f ? v : 0.2f * v; }
__device__ __forceinline__ ushort_t f2b(float x) {
  unsigned u = __float_as_uint(x);
  return (ushort_t)((u + 0x7FFFu + ((u >> 16) & 1u)) >> 16);
}
__device__ __forceinline__ float b2f(ushort_t u) {
  return __uint_as_float(((unsigned)u) << 16);
}
__device__ __forceinline__ ushort_t f2h(float x) {
  return __half_as_ushort(__float2half_rn(x));
}
__device__ __forceinline__ float h2f(unsigned u) {
  return __half2float(__ushort_as_half((ushort_t)(u & 0xFFFFu)));
}
__device__ __forceinline__ float sel4(float a, float b, float c, float d, int h) {
  float ab = (h & 1) ? b : a;
  float cd = (h & 1) ? d : c;
  return (h & 2) ? cd : ab;
}
__device__ __forceinline__ bf16x8 pack8(float4 a, float4 b) {
  bf16x8 r;
  r[0] = (short)f2b(a.x); r[1] = (short)f2b(a.y);
  r[2] = (short)f2b(a.z); r[3] = (short)f2b(a.w);
  r[4] = (short)f2b(b.x); r[5] = (short)f2b(b.y);
  r[6] = (short)f2b(b.z); r[7] = (short)f2b(b.w);
  return r;
}

// ---------- graph prep: atomic-free two-level counting sort by dst ----------

// Coarse histogram: 250 blocks x 3200 edges, 196 bins (dst>>8) in LDS.
__global__ void __launch_bounds__(256) k_hist196(const int* __restrict__ ei,
                                                 int* __restrict__ histG) {
  __shared__ int h[NBIN];
  int blk = blockIdx.x;
  for (int j = threadIdx.x; j < NBIN; j += 256) h[j] = 0;
  __syncthreads();
  int e0 = blk * EPB;
  for (int e = e0 + threadIdx.x; e < e0 + EPB; e += 256)
    atomicAdd(&h[ei[NE + e] >> 8], 1);
  __syncthreads();
  for (int j = threadIdx.x; j < NBIN; j += 256) histG[j * NB1 + blk] = h[j];
}

// Hierarchical exclusive scan over the bin-major count matrix (padded to STOT).
__global__ void __launch_bounds__(256) k_scanMA(int* __restrict__ histG,
                                                int* __restrict__ bsum) {
  __shared__ int sm[256];
  int j = threadIdx.x;
  int i = blockIdx.x * 256 + j;
  const int TOT = NBIN * NB1;
  int v = (i < TOT) ? histG[i] : 0;
  sm[j] = v;
  __syncthreads();
  for (int off = 1; off < 256; off <<= 1) {
    int t = (j >= off) ? sm[j - off] : 0;
    __syncthreads();
    sm[j] += t;
    __syncthreads();
  }
  if (i < TOT) histG[i] = sm[j] - v;  // block-local exclusive
  if (j == 255) bsum[blockIdx.x] = sm[255];
}

__global__ void __launch_bounds__(256) k_scanMB(int* __restrict__ bsum,
                                                float* __restrict__ scal) {
  __shared__ int sm[256];
  int j = threadIdx.x;
  for (int t = j; t < 1024; t += 256) scal[t] = 0.f;
  int v = (j < SBLK) ? bsum[j] : 0;
  sm[j] = v;
  __syncthreads();
  for (int off = 1; off < 256; off <<= 1) {
    int t = (j >= off) ? sm[j - off] : 0;
    __syncthreads();
    sm[j] += t;
    __syncthreads();
  }
  if (j < SBLK) bsum[j] = sm[j] - v;
}

__global__ void __launch_bounds__(256) k_scanMC(int* __restrict__ histG,
                                                const int* __restrict__ bsum) {
  int i = blockIdx.x * 256 + threadIdx.x;
  const int TOT = NBIN * NB1;
  if (i < TOT) histG[i] += bsum[i >> 8];
}

// Partition pass: scatter packed temp records into per-(bin,block) exclusive
// regions via LDS cursors (no global atomics). Also accumulates edge_attr sum.
// temp record: x = src | f16(ew)<<16 ; y = (dst&0xFF) | f16(ea)<<16
__global__ void __launch_bounds__(256) k_part(
    const int* __restrict__ ei, const float* __restrict__ ew,
    const float* __restrict__ ea, const int* __restrict__ histG,
    uint2* __restrict__ rectmp, float* __restrict__ scal) {
  __shared__ int cur[NBIN];
  int blk = blockIdx.x;
  for (int j = threadIdx.x; j < NBIN; j += 256) cur[j] = histG[j * NB1 + blk];
  __syncthreads();
  int e0 = blk * EPB;
  float asum = 0.f;
  for (int e = e0 + threadIdx.x; e < e0 + EPB; e += 256) {
    int src = ei[e];
    int dst = ei[NE + e];
    float w = ew[e];
    float a = ea[e];
    asum += a;
    int slot = atomicAdd(&cur[dst >> 8], 1);
    uint2 r;
    r.x = (uint_t)(src & 0xFFFF) | ((uint_t)f2h(w) << 16);
    r.y = (uint_t)(dst & 0xFF) | ((uint_t)f2h(a) << 16);
    rectmp[slot] = r;
  }
  float s = wave_sum64(asum);
  if ((threadIdx.x & 63) == 0) {
    int slot = (blk * 4 + (threadIdx.x >> 6)) & 63;
    atomicAdd(&scal[(size_t)slot * 16], s);
  }
}

// Final counting sort within each coarse bucket (one block per bucket):
// emits final rec (x=src|f16w, y=src|f16ea) grouped by dst, and rs[] directly.
__global__ void __launch_bounds__(256) k_sortfin(
    const uint2* __restrict__ rectmp, const int* __restrict__ histG,
    uint2* __restrict__ rec, int* __restrict__ rs) {
  __shared__ int cnt[256], sc[256], cur[256];
  int b = blockIdx.x;
  int t = threadIdx.x;
  int lo = histG[b * NB1];
  int hi = (b == NBIN - 1) ? NE : histG[(b + 1) * NB1];
  cnt[t] = 0;
  __syncthreads();
  for (int e = lo + t; e < hi; e += 256)
    atomicAdd(&cnt[rectmp[e].y & 0xFFu], 1);
  __syncthreads();
  int v = cnt[t];
  sc[t] = v;
  __syncthreads();
  for (int off = 1; off < 256; off <<= 1) {
    int u = (t >= off) ? sc[t - off] : 0;
    __syncthreads();
    sc[t] += u;
    __syncthreads();
  }
  int ex = sc[t] - v;  // exclusive within bucket
  int node = b * 256 + t;
  if (node < NN) rs[node] = lo + ex;
  if (b == NBIN - 1 && t == 0) rs[NN] = NE;
  cur[t] = lo + ex;
  __syncthreads();
  for (int e = lo + t; e < hi; e += 256) {
    uint2 r = rectmp[e];
    int dl = (int)(r.y & 0xFFu);
    int slot = atomicAdd(&cur[dl], 1);
    uint_t src = r.x & 0xFFFFu;
    uint2 o;
    o.x = r.x;
    o.y = src | (r.y & 0xFFFF0000u);
    rec[slot] = o;
  }
}

// deg from CSR (contiguous reads); thread 0 finalizes mean edge_attr
__global__ void k_deg(const uint_t* __restrict__ rec, const int* __restrict__ rs,
                      float* __restrict__ dinv, float* __restrict__ scal) {
  int i = blockIdx.x * blockDim.x + threadIdx.x;
  if (i < NN) {
    float s = 1.f;
    int k1 = rs[i + 1];
    for (int k = rs[i]; k < k1; ++k) s += h2f(rec[2 * k] >> 16);
    dinv[i] = rsqrtf(s);
  }
  if (i == 0) {
    float t = 0.f;
    for (int j = 0; j < 64; ++j) t += scal[(size_t)j * 16];
    scal[1] = t / (float)NE;
  }
}

// ---------- MFMA dense ops ----------
__global__ void __launch_bounds__(256) k_dual_gemm(
    const float* __restrict__ x, const float* __restrict__ W1,
    const float* __restrict__ W2, const float* __restrict__ b2,
    ushort_t* __restrict__ out1, float* __restrict__ out2) {
  __shared__ ushort_t wf[2 * 2 * 4 * 512];
  for (int e = threadIdx.x; e < 8192; e += 256) {
    int f = e >> 9, r = e & 511;
    int lane = r >> 3, j = r & 7;
    int m = f >> 3, s = (f >> 2) & 1, t = f & 3;
    int k = s * 32 + (lane >> 4) * 8 + j;
    int n = t * 16 + (lane & 15);
    const float* Wm = m ? W2 : W1;
    wf[e] = f2b(Wm[k * D + n]);
  }
  __syncthreads();
  int tile = blockIdx.x * 4 + (threadIdx.x >> 6);
  if (tile >= NT) return;
  int l = threadIdx.x & 63;
  int q = l >> 4, cn = l & 15;
  const float* xr = x + ((size_t)tile * 16 + cn) * D + q * 8;
  float4 xa = *(const float4*)xr;
  float4 xb = *(const float4*)(xr + 4);
  float4 xc = *(const float4*)(xr + 32);
  float4 xd = *(const float4*)(xr + 36);
  bf16x8 a0 = pack8(xa, xb), a1 = pack8(xc, xd);
  f32x4 acc1[4], acc2[4];
#pragma unroll
  for (int t = 0; t < 4; ++t) {
    bf16x8 b10 = *(const bf16x8*)&wf[(0 * 8 + 0 * 4 + t) * 512 + l * 8];
    bf16x8 b11 = *(const bf16x8*)&wf[(0 * 8 + 1 * 4 + t) * 512 + l * 8];
    bf16x8 b20 = *(const bf16x8*)&wf[(1 * 8 + 0 * 4 + t) * 512 + l * 8];
    bf16x8 b21 = *(const bf16x8*)&wf[(1 * 8 + 1 * 4 + t) * 512 + l * 8];
    f32x4 z = {0.f, 0.f, 0.f, 0.f};
    acc1[t] = __builtin_amdgcn_mfma_f32_16x16x32_bf16(a0, b10, z, 0, 0, 0);
    acc1[t] = __builtin_amdgcn_mfma_f32_16x16x32_bf16(a1, b11, acc1[t], 0, 0, 0);
    acc2[t] = __builtin_amdgcn_mfma_f32_16x16x32_bf16(a0, b20, z, 0, 0, 0);
    acc2[t] = __builtin_amdgcn_mfma_f32_16x16x32_bf16(a1, b21, acc2[t], 0, 0, 0);
  }
#pragma unroll
  for (int t = 0; t < 4; ++t) {
    float bb = b2[t * 16 + cn];
#pragma unroll
    for (int r = 0; r < 4; ++r) {
      size_t row = (size_t)tile * 16 + q * 4 + r;
      out1[row * D + t * 16 + cn] = f2b(acc1[t][r]);
      out2[row * D + t * 16 + cn] = acc2[t][r] + bb;
    }
  }
}

__global__ void __launch_bounds__(256) k_gat_node(
    const float* __restrict__ x2, const float* __restrict__ Wg,
    const float* __restrict__ att_src, const float* __restrict__ att_dst,
    const float* __restrict__ We, const float* __restrict__ a_e,
    ushort_t* __restrict__ xl, float* __restrict__ a_s, float* __restrict__ a_d,
    float* __restrict__ wea) {
  __shared__ ushort_t wf[2 * 4 * 512];
  for (int e = threadIdx.x; e < 4096; e += 256) {
    int f = e >> 9, r = e & 511;
    int lane = r >> 3, j = r & 7;
    int s = (f >> 2) & 1, t = f & 3;
    int k = s * 32 + (lane >> 4) * 8 + j;
    int n = t * 16 + (lane & 15);
    wf[e] = f2b(Wg[k * D + n]);
  }
  __syncthreads();
  if (blockIdx.x == 0 && threadIdx.x < 64) {
    int c = threadIdx.x;
    float v = group_sum16(We[c] * a_e[c]);
    if ((c & 15) == 0) wea[c >> 4] = v;
  }
  int tile = blockIdx.x * 4 + (threadIdx.x >> 6);
  if (tile >= NT) return;
  int l = threadIdx.x & 63;
  int q = l >> 4, cn = l & 15;
  const float* xr = x2 + ((size_t)tile * 16 + cn) * D + q * 8;
  float4 xa = *(const float4*)xr;
  float4 xb = *(const float4*)(xr + 4);
  float4 xc = *(const float4*)(xr + 32);
  float4 xd = *(const float4*)(xr + 36);
  bf16x8 a0 = pack8(xa, xb), a1 = pack8(xc, xd);
  f32x4 acc[4];
#pragma unroll
  for (int t = 0; t < 4; ++t) {
    bf16x8 b0 = *(const bf16x8*)&wf[(0 * 4 + t) * 512 + l * 8];
    bf16x8 b1 = *(const bf16x8*)&wf[(1 * 4 + t) * 512 + l * 8];
    f32x4 z = {0.f, 0.f, 0.f, 0.f};
    acc[t] = __builtin_amdgcn_mfma_f32_16x16x32_bf16(a0, b0, z, 0, 0, 0);
    acc[t] = __builtin_amdgcn_mfma_f32_16x16x32_bf16(a1, b1, acc[t], 0, 0, 0);
  }
#pragma unroll
  for (int t = 0; t < 4; ++t) {
    float av = att_src[t * 16 + cn];
    float dv = att_dst[t * 16 + cn];
#pragma unroll
    for (int r = 0; r < 4; ++r) {
      size_t row = (size_t)tile * 16 + q * 4 + r;
      xl[row * D + t * 16 + cn] = f2b(acc[t][r]);
      float vs = group_sum16(acc[t][r] * av);
      float vd = group_sum16(acc[t][r] * dv);
      if (cn == 0) {
        a_s[row * 4 + t] = vs;
        a_d[row * 4 + t] = vd;
      }
    }
  }
}

// ---------- aggregation kernels (2 nodes per wave) ----------

__global__ void __launch_bounds__(256) k_gcn_agg(
    const ushort_t* __restrict__ h16, const float* __restrict__ res,
    const float* __restrict__ dinv, const int* __restrict__ rs,
    const uint_t* __restrict__ rec,
    const float* __restrict__ gb, const float* __restrict__ lg, const float* __restrict__ lb,
    float* __restrict__ x2, int n) {
  __shared__ int   ss[4][64];
  __shared__ float swt[4][64];
  int w = threadIdx.x >> 6;
  int wv = (blockIdx.x * blockDim.x + threadIdx.x) >> 6;
  int iA = wv * 2;
  if (iA >= n) return;
  int iB = iA + 1;
  int l = threadIdx.x & 63;
  int half = l >> 5, cp = l & 31;
  float diA = dinv[iA], diB = dinv[iB];
  float accA = diA * diA * b2f(h16[(size_t)iA * D + l]);
  float accB = diB * diB * b2f(h16[(size_t)iB * D + l]);
  int kA = rs[iA], kA1 = rs[iA + 1];
  int kB = rs[iB], kB1 = rs[iB + 1];
  while (kA < kA1 || kB < kB1) {
    int cntA = min(32, kA1 - kA);
    int cntB = min(32, kB1 - kB);
    int src = 0; float wn = 0.f;
    if (half == 0) {
      if (cp < cntA) {
        uint_t r = rec[2 * (size_t)(kA + cp)];
        src = (int)(r & 0xFFFFu);
        wn = dinv[src] * h2f(r >> 16) * diA;
      }
    } else {
      if (cp < cntB) {
        uint_t r = rec[2 * (size_t)(kB + cp)];
        src = (int)(r & 0xFFFFu);
        wn = dinv[src] * h2f(r >> 16) * diB;
      }
    }
    ss[w][l] = src;
    swt[w][l] = wn;
    int nm = max(cntA, cntB);
    int j = 0;
    for (; j + 4 <= nm; j += 4) {
      int4 sa = *(const int4*)&ss[w][j];
      int4 sb = *(const int4*)&ss[w][32 + j];
      float4 wa = *(const float4*)&swt[w][j];
      float4 wb = *(const float4*)&swt[w][32 + j];
      float a0 = b2f(h16[(size_t)sa.x * D + l]);
      float b0 = b2f(h16[(size_t)sb.x * D + l]);
      float a1 = b2f(h16[(size_t)sa.y * D + l]);
      float b1 = b2f(h16[(size_t)sb.y * D + l]);
      float a2 = b2f(h16[(size_t)sa.z * D + l]);
      float b2v = b2f(h16[(size_t)sb.z * D + l]);
      float a3 = b2f(h16[(size_t)sa.w * D + l]);
      float b3 = b2f(h16[(size_t)sb.w * D + l]);
      accA = fmaf(wa.x, a0, accA); accB = fmaf(wb.x, b0, accB);
      accA = fmaf(wa.y, a1, accA); accB = fmaf(wb.y, b1, accB);
      accA = fmaf(wa.z, a2, accA); accB = fmaf(wb.z, b2v, accB);
      accA = fmaf(wa.w, a3, accA); accB = fmaf(wb.w, b3, accB);
    }
    for (; j < nm; ++j) {
      int sA = ss[w][j], sB = ss[w][32 + j];
      float wA = swt[w][j], wB = swt[w][32 + j];
      float vA = b2f(h16[(size_t)sA * D + l]);
      float vB = b2f(h16[(size_t)sB * D + l]);
      accA = fmaf(wA, vA, accA);
      accB = fmaf(wB, vB, accB);
    }
    kA += cntA; kB += cntB;
  }
  float gbv = gb[l], lgv = lg[l], lbv = lb[l];
  float x1A = silu_f(accA + gbv) + res[(size_t)iA * D + l];
  float x1B = silu_f(accB + gbv) + res[(size_t)iB * D + l];
  float muA = wave_sum64(x1A) * (1.f / 64.f);
  float muB = wave_sum64(x1B) * (1.f / 64.f);
  float dA = x1A - muA, dB = x1B - muB;
  float varA = wave_sum64(dA * dA) * (1.f / 64.f);
  float varB = wave_sum64(dB * dB) * (1.f / 64.f);
  x2[(size_t)iA * D + l] = dA * rsqrtf(varA + EPS) * lgv + lbv;
  x2[(size_t)iB * D + l] = dB * rsqrtf(varB + EPS) * lgv + lbv;
}

__global__ void __launch_bounds__(256) k_gat_agg(
    const ushort_t* __restrict__ xl16, const float* __restrict__ x2,
    const float* __restrict__ a_s, const float* __restrict__ a_d,
    const int* __restrict__ rs, const uint_t* __restrict__ rec,
    const float* __restrict__ wea, const float* __restrict__ scal,
    const float* __restrict__ bg, float* __restrict__ xout, int n) {
  __shared__ int   ss[4][64];
  __shared__ float el[4][4][68];
  int w = threadIdx.x >> 6;
  int wv = (blockIdx.x * blockDim.x + threadIdx.x) >> 6;
  int iA = wv * 2;
  if (iA >= n) return;
  int iB = iA + 1;
  int l = threadIdx.x & 63;
  int half = l >> 5, cp = l & 31;
  int hh = l >> 4;
  float4 wv4 = *(const float4*)wea;
  float mean_attr = scal[1];
  float we_h = sel4(wv4.x, wv4.y, wv4.z, wv4.w, hh);
  float ad_hA = a_d[(size_t)iA * 4 + hh], as_iA = a_s[(size_t)iA * 4 + hh];
  float ad_hB = a_d[(size_t)iB * 4 + hh], as_iB = a_s[(size_t)iB * 4 + hh];
  float eSA = __expf(lrelu_f(as_iA + ad_hA + mean_attr * we_h));
  float eSB = __expf(lrelu_f(as_iB + ad_hB + mean_attr * we_h));
  float sA = eSA, sB = eSB;
  float accA = eSA * b2f(xl16[(size_t)iA * D + l]);
  float accB = eSB * b2f(xl16[(size_t)iB * D + l]);
  const float* adp = a_d + (size_t)(half ? iB : iA) * 4;
  float4 ad4 = *(const float4*)adp;
  int kA = rs[iA], kA1 = rs[iA + 1];
  int kB = rs[iB], kB1 = rs[iB + 1];
  while (kA < kA1 || kB < kB1) {
    int cntA = min(32, kA1 - kA);
    int cntB = min(32, kB1 - kB);
    int myk = half ? kB : kA;
    int mycnt = half ? cntB : cntA;
    int src = 0;
    float e0v = 0.f, e1v = 0.f, e2v = 0.f, e3v = 0.f;
    if (cp < mycnt) {
      uint_t r = rec[2 * (size_t)(myk + cp) + 1];
      src = (int)(r & 0xFFFFu);
      float ea = h2f(r >> 16);
      float4 as4 = *(const float4*)(a_s + (size_t)src * 4);
      e0v = __expf(lrelu_f(as4.x + fmaf(ea, wv4.x, ad4.x)));
      e1v = __expf(lrelu_f(as4.y + fmaf(ea, wv4.y, ad4.y)));
      e2v = __expf(lrelu_f(as4.z + fmaf(ea, wv4.z, ad4.z)));
      e3v = __expf(lrelu_f(as4.w + fmaf(ea, wv4.w, ad4.w)));
    }
    ss[w][l] = src;
    el[w][0][l] = e0v;
    el[w][1][l] = e1v;
    el[w][2][l] = e2v;
    el[w][3][l] = e3v;
    int nm = max(cntA, cntB);
    int j = 0;
    for (; j + 4 <= nm; j += 4) {
      int4 sa = *(const int4*)&ss[w][j];
      int4 sb = *(const int4*)&ss[w][32 + j];
      float4 ea4 = *(const float4*)&el[w][hh][j];
      float4 eb4 = *(const float4*)&el[w][hh][32 + j];
      float a0 = b2f(xl16[(size_t)sa.x * D + l]);
      float b0 = b2f(xl16[(size_t)sb.x * D + l]);
      float a1 = b2f(xl16[(size_t)sa.y * D + l]);
      float b1 = b2f(xl16[(size_t)sb.y * D + l]);
      float a2 = b2f(xl16[(size_t)sa.z * D + l]);
      float b2v = b2f(xl16[(size_t)sb.z * D + l]);
      float a3 = b2f(xl16[(size_t)sa.w * D + l]);
      float b3 = b2f(xl16[(size_t)sb.w * D + l]);
      accA = fmaf(ea4.x, a0, accA); accB = fmaf(eb4.x, b0, accB);
      accA = fmaf(ea4.y, a1, accA); accB = fmaf(eb4.y, b1, accB);
      accA = fmaf(ea4.z, a2, accA); accB = fmaf(eb4.z, b2v, accB);
      accA = fmaf(ea4.w, a3, accA); accB = fmaf(eb4.w, b3, accB);
      sA += (ea4.x + ea4.y) + (ea4.z + ea4.w);
      sB += (eb4.x + eb4.y) + (eb4.z + eb4.w);
    }
    for (; j < nm; ++j) {
      int srcA = ss[w][j], srcB = ss[w][32 + j];
      float eA = el[w][hh][j], eB = el[w][hh][32 + j];
      float vA = b2f(xl16[(size_t)srcA * D + l]);
      float vB = b2f(xl16[(size_t)srcB * D + l]);
      accA = fmaf(eA, vA, accA);
      accB = fmaf(eB, vB, accB);
      sA += eA; sB += eB;
    }
    kA += cntA; kB += cntB;
  }
  float bgv = bg[l];
  float oA = accA / (sA + 1e-16f) + bgv;
  float oB = accB / (sB + 1e-16f) + bgv;
  xout[(size_t)iA * D + l] = silu_f(oA) + x2[(size_t)iA * D + l];
  xout[(size_t)iB * D + l] = silu_f(oB) + x2[(size_t)iB * D + l];
}

// ---------- launch ----------

extern "C" void kernel_launch(void* const* d_in, const int* in_sizes, int n_in,
                              void* d_out, int out_size, void* d_ws, size_t ws_size,
                              hipStream_t stream) {
  (void)in_sizes; (void)n_in; (void)out_size; (void)ws_size;
  const float* x  = (const float*)d_in[0];
  const int*   ei = (const int*)d_in[1];
  const float* ew = (const float*)d_in[2];
  const float* ea = (const float*)d_in[3];
  const float* P[2][12];
  for (int l = 0; l < 2; ++l)
    for (int j = 0; j < 12; ++j) P[l][j] = (const float*)d_in[4 + l * 12 + j];

  float* W = (float*)d_ws;
  const size_t o_rs    = 0;                          // NN+16 ints
  const size_t o_dinv  = o_rs + NN + 16;             // NN
  const size_t o_wea   = o_dinv + NN;                // 16
  const size_t o_scal  = o_wea + 16;                 // 1024
  const size_t o_bsum  = o_scal + 1024;              // 256
  const size_t o_hist  = o_bsum + 256;               // STOT ints
  const size_t o_rec   = o_hist + STOT;              // NE uint2
  const size_t o_rtmp  = o_rec + (size_t)NE * 2;     // NE uint2
  const size_t o_h16   = o_rtmp + (size_t)NE * 2;    // NN*D ushort
  const size_t o_xl16  = o_h16 + (size_t)NN * D / 2;
  const size_t o_res   = o_xl16 + (size_t)NN * D / 2;
  const size_t o_x2    = o_res + (size_t)NN * D;
  const size_t o_xmid  = o_x2 + (size_t)NN * D;
  const size_t o_as    = o_xmid + (size_t)NN * D;    // NN*4
  const size_t o_ad    = o_as + (size_t)NN * 4;      // NN*4

  int*      rs    = (int*)(W + o_rs);
  float*    dinv  = W + o_dinv;
  float*    wea   = W + o_wea;
  float*    scal  = W + o_scal;
  int*      bsum  = (int*)(W + o_bsum);
  int*      histG = (int*)(W + o_hist);
  uint2*    rec   = (uint2*)(W + o_rec);
  uint2*    rtmp  = (uint2*)(W + o_rtmp);
  ushort_t* h16   = (ushort_t*)(W + o_h16);
  ushort_t* xl16  = (ushort_t*)(W + o_xl16);
  float*    resb  = W + o_res;
  float*    x2b   = W + o_x2;
  float*    xmid  = W + o_xmid;
  float*    asb   = W + o_as;
  float*    adb   = W + o_ad;

  const int B = 256;
  const int gN  = (NN + B - 1) / B;
  const int gN2 = ((NN / 2) * 64 + B - 1) / B;  // 2 nodes per wave (agg kernels)
  const int gMF = (NT + 3) / 4;                 // 4 MFMA tiles per block

  k_hist196<<<NB1, B, 0, stream>>>(ei, histG);
  k_scanMA<<<SBLK, B, 0, stream>>>(histG, bsum);
  k_scanMB<<<1, B, 0, stream>>>(bsum, scal);
  k_scanMC<<<SBLK, B, 0, stream>>>(histG, bsum);
  k_part<<<NB1, B, 0, stream>>>(ei, ew, ea, histG, rtmp, scal);
  k_sortfin<<<NBIN, B, 0, stream>>>(rtmp, histG, rec, rs);
  k_deg<<<gN, B, 0, stream>>>((const uint_t*)rec, rs, dinv, scal);

  const float* xin = x;
  for (int l = 0; l < 2; ++l) {
    float* xout = (l == 0) ? xmid : (float*)d_out;
    k_dual_gemm<<<gMF, B, 0, stream>>>(xin, P[l][0], P[l][2], P[l][3], h16, resb);
    k_gcn_agg<<<gN2, B, 0, stream>>>(h16, resb, dinv, rs, (const uint_t*)rec,
                                     P[l][1], P[l][4], P[l][5], x2b, NN);
    k_gat_node<<<gMF, B, 0, stream>>>(x2b, P[l][6], P[l][8], P[l][9],
                                      P[l][11], P[l][10], xl16, asb, adb, wea);
    k_gat_agg<<<gN2, B, 0, stream>>>(xl16, x2b, asb, adb, rs, (const uint_t*)rec,
                                     wea, scal, P[l][7], xout, NN);
    xin = xout;
  }
}